// Round 7
// baseline (409.815 us; speedup 1.0000x reference)
//
#include <hip/hip_runtime.h>

#define N_NODES 100000
#define N_EDGES 1600000
#define D_IN 128
#define D_HID 128
#define D_LAT 64

#define BSHIFT 8                          // 256 nodes per bucket
#define NB 392                            // ceil(100352 / 256) buckets
#define CAP 4608                          // slots per bucket region (mean 4082 + 8.2 sigma)
#define EPB 4096                          // edges per partition block
#define PART_BLOCKS ((N_EDGES + EPB - 1) / EPB)   // 391

typedef unsigned short ushort_t;
typedef unsigned int uint_t;
using bf16x8 = __attribute__((ext_vector_type(8))) short;
using f32x4  = __attribute__((ext_vector_type(4))) float;

__device__ inline ushort_t f2bf(float f) {
    uint_t u = __float_as_uint(f);
    return (ushort_t)((u + 0x7fffu + ((u >> 16) & 1u)) >> 16);   // RNE
}
__device__ inline uint_t pack2bf(float a, float b) {
    return (uint_t)f2bf(a) | ((uint_t)f2bf(b) << 16);
}
__device__ inline float bf2f(ushort_t u) {
    return __uint_as_float(((uint_t)u) << 16);
}

// ---------------- CSR build: fixed-stride bucketed counting sort ----------------
__global__ void init_cursor_kernel(int* __restrict__ gCur) {
    int t = blockIdx.x * blockDim.x + threadIdx.x;
    if (t < NB) gCur[t] = t * CAP;
}

__global__ __launch_bounds__(256) void bucket_scatter_kernel(const int* __restrict__ src,
                                                             const int* __restrict__ dst,
                                                             int* __restrict__ gCur,
                                                             int* __restrict__ bedges) {
    __shared__ int h[NB];
    __shared__ int start[NB];
    for (int j = threadIdx.x; j < NB; j += 256) h[j] = 0;
    __syncthreads();
    long base = (long)blockIdx.x * EPB;
    #pragma unroll
    for (int i = 0; i < EPB / 256; ++i) {
        long e = base + i * 256 + threadIdx.x;
        if (e < N_EDGES) atomicAdd(&h[dst[e] >> BSHIFT], 1);
    }
    __syncthreads();
    for (int j = threadIdx.x; j < NB; j += 256)
        start[j] = h[j] ? atomicAdd(&gCur[j], h[j]) : 0;
    __syncthreads();
    #pragma unroll
    for (int i = 0; i < EPB / 256; ++i) {
        long e = base + i * 256 + threadIdx.x;
        if (e < N_EDGES) {
            int d = dst[e];
            int b = d >> BSHIFT;
            int p = atomicAdd(&start[b], 1);
            if (p < (b + 1) * CAP)                     // overflow clamp (P ~ 1e-16)
                bedges[p] = ((d & 255) << 24) | src[e];
        }
    }
}

__global__ __launch_bounds__(256) void bucket_sort_kernel(const int* __restrict__ gCur,
                                                          const int* __restrict__ bedges,
                                                          int* __restrict__ csr,
                                                          int2* __restrict__ off2) {
    __shared__ int sdata[256];
    __shared__ int cur[256];
    int b = blockIdx.x, t = threadIdx.x;
    int r0 = b * CAP;
    int n = gCur[b] - r0;
    if (n > CAP) n = CAP;
    cur[t] = 0;
    __syncthreads();
    for (int k = t; k < n; k += 256) atomicAdd(&cur[(unsigned)bedges[r0 + k] >> 24], 1);
    __syncthreads();
    int c = cur[t];
    sdata[t] = c;
    __syncthreads();
    for (int d = 1; d < 256; d <<= 1) {
        int u = (t >= d) ? sdata[t - d] : 0;
        __syncthreads();
        sdata[t] += u;
        __syncthreads();
    }
    int ex = (t == 0) ? 0 : sdata[t - 1];
    off2[(b << BSHIFT) + t] = make_int2(r0 + ex, c);
    cur[t] = ex;
    __syncthreads();
    for (int k = t; k < n; k += 256) {
        int v = bedges[r0 + k];
        int p = atomicAdd(&cur[(unsigned)v >> 24], 1);
        csr[r0 + p] = v & 0xFFFFFF;
    }
}

// ---------------- fp32 -> bf16 slice-major convert ----------------
// xs layout: [8 slices][N_NODES][16 bf16]; slice s holds dims [s*16, s*16+16)
__global__ __launch_bounds__(256) void cvt_slice_kernel(const float* __restrict__ x,
                                                        ushort_t* __restrict__ xs) {
    int t = threadIdx.x;
    int s = t >> 5;
    long i = (long)blockIdx.x * 32 + (t & 31);
    if (i >= N_NODES) return;
    const float4* px = (const float4*)(x + i * 128 + s * 16);
    float4 a = px[0], b = px[1], c = px[2], d = px[3];
    uint4 o0, o1;
    o0.x = pack2bf(a.x, a.y); o0.y = pack2bf(a.z, a.w);
    o0.z = pack2bf(b.x, b.y); o0.w = pack2bf(b.z, b.w);
    o1.x = pack2bf(c.x, c.y); o1.y = pack2bf(c.z, c.w);
    o1.z = pack2bf(d.x, d.y); o1.w = pack2bf(d.z, d.w);
    ushort_t* dstp = xs + ((long)s * N_NODES + i) * 16;
    *(uint4*)dstp = o0;
    *(uint4*)(dstp + 8) = o1;
}

// ---------------- pack [Wl;Wr] (K=256 x N) into MFMA B-fragment order ----------------
__global__ void pack_w_kernel(const float* __restrict__ Wl, const float* __restrict__ Wr,
                              ushort_t* __restrict__ pack, int N) {
    int tid = blockIdx.x * blockDim.x + threadIdx.x;
    int total = (N / 16) * 8 * 64;
    if (tid >= total) return;
    int lane = tid & 63;
    int t = tid >> 6;
    int kt = t & 7;
    int nt = t >> 3;
    int n = nt * 16 + (lane & 15);
    int kbase = kt * 32 + (lane >> 4) * 8;
    ushort_t v[8];
    #pragma unroll
    for (int j = 0; j < 8; ++j) {
        int k = kbase + j;
        float w = (k < 128) ? Wl[k * N + n] : Wr[(k - 128) * N + n];
        v[j] = f2bf(w);
    }
    *(uint4*)(pack + (long)tid * 8) = *(uint4*)v;
}

__global__ void pack_wk128_kernel(const float* __restrict__ W, ushort_t* __restrict__ pack, int N) {
    int tid = blockIdx.x * blockDim.x + threadIdx.x;
    int total = (N / 16) * 4 * 64;
    if (tid >= total) return;
    int lane = tid & 63;
    int t = tid >> 6;
    int kt = t & 3;
    int nt = t >> 2;
    int n = nt * 16 + (lane & 15);
    int kbase = kt * 32 + (lane >> 4) * 8;
    ushort_t v[8];
    #pragma unroll
    for (int j = 0; j < 8; ++j) v[j] = f2bf(W[(kbase + j) * N + n]);
    *(uint4*)(pack + (long)tid * 8) = *(uint4*)v;
}

// ---------------- XCD-affine sliced gather-mean, 128-dim ----------------
// slice = blockIdx%8 (-> XCD via round-robin), 32 B of each row; 2 lanes/node.
__global__ __launch_bounds__(256) void gather_slice128_kernel(
        const int2* __restrict__ off2, const int* __restrict__ csr_src,
        const ushort_t* __restrict__ xs, ushort_t* __restrict__ mean_s) {
    int s = blockIdx.x & 7;
    int grp = blockIdx.x >> 3;
    int t = threadIdx.x;
    int half = t & 1;
    long i = (long)grp * 128 + (t >> 1);
    if (i >= N_NODES) return;
    int2 bd = off2[i];
    const ushort_t* base = xs + (long)s * N_NODES * 16 + half * 8;
    float acc[8] = {0.f, 0.f, 0.f, 0.f, 0.f, 0.f, 0.f, 0.f};
    int k = 0;
    for (; k + 2 <= bd.y; k += 2) {
        int s0 = csr_src[bd.x + k];
        int s1 = csr_src[bd.x + k + 1];
        uint4 u0 = *(const uint4*)(base + (long)s0 * 16);
        uint4 u1 = *(const uint4*)(base + (long)s1 * 16);
        acc[0] += __uint_as_float(u0.x << 16);       acc[1] += __uint_as_float(u0.x & 0xffff0000u);
        acc[2] += __uint_as_float(u0.y << 16);       acc[3] += __uint_as_float(u0.y & 0xffff0000u);
        acc[4] += __uint_as_float(u0.z << 16);       acc[5] += __uint_as_float(u0.z & 0xffff0000u);
        acc[6] += __uint_as_float(u0.w << 16);       acc[7] += __uint_as_float(u0.w & 0xffff0000u);
        acc[0] += __uint_as_float(u1.x << 16);       acc[1] += __uint_as_float(u1.x & 0xffff0000u);
        acc[2] += __uint_as_float(u1.y << 16);       acc[3] += __uint_as_float(u1.y & 0xffff0000u);
        acc[4] += __uint_as_float(u1.z << 16);       acc[5] += __uint_as_float(u1.z & 0xffff0000u);
        acc[6] += __uint_as_float(u1.w << 16);       acc[7] += __uint_as_float(u1.w & 0xffff0000u);
    }
    if (k < bd.y) {
        int s0 = csr_src[bd.x + k];
        uint4 u0 = *(const uint4*)(base + (long)s0 * 16);
        acc[0] += __uint_as_float(u0.x << 16);       acc[1] += __uint_as_float(u0.x & 0xffff0000u);
        acc[2] += __uint_as_float(u0.y << 16);       acc[3] += __uint_as_float(u0.y & 0xffff0000u);
        acc[4] += __uint_as_float(u0.z << 16);       acc[5] += __uint_as_float(u0.z & 0xffff0000u);
        acc[6] += __uint_as_float(u0.w << 16);       acc[7] += __uint_as_float(u0.w & 0xffff0000u);
    }
    float inv = (bd.y > 0) ? 1.f / (float)bd.y : 0.f;
    uint4 o;
    o.x = pack2bf(acc[0] * inv, acc[1] * inv);
    o.y = pack2bf(acc[2] * inv, acc[3] * inv);
    o.z = pack2bf(acc[4] * inv, acc[5] * inv);
    o.w = pack2bf(acc[6] * inv, acc[7] * inv);
    *(uint4*)(mean_s + ((long)s * N_NODES + i) * 16 + half * 8) = o;
}

// ---------------- XCD-affine sliced gather-mean, 64-dim ----------------
// g layout: [8 slices][N_NODES][8 bf16]; output meang row-major [N][64].
__global__ __launch_bounds__(256) void gather_slice64_kernel(
        const int2* __restrict__ off2, const int* __restrict__ csr_src,
        const ushort_t* __restrict__ gs, ushort_t* __restrict__ meang) {
    int s = blockIdx.x & 7;
    int grp = blockIdx.x >> 3;
    long i = (long)grp * 256 + threadIdx.x;
    if (i >= N_NODES) return;
    int2 bd = off2[i];
    const ushort_t* base = gs + (long)s * N_NODES * 8;
    float acc[8] = {0.f, 0.f, 0.f, 0.f, 0.f, 0.f, 0.f, 0.f};
    int k = 0;
    for (; k + 2 <= bd.y; k += 2) {
        int s0 = csr_src[bd.x + k];
        int s1 = csr_src[bd.x + k + 1];
        uint4 u0 = *(const uint4*)(base + (long)s0 * 8);
        uint4 u1 = *(const uint4*)(base + (long)s1 * 8);
        acc[0] += __uint_as_float(u0.x << 16);       acc[1] += __uint_as_float(u0.x & 0xffff0000u);
        acc[2] += __uint_as_float(u0.y << 16);       acc[3] += __uint_as_float(u0.y & 0xffff0000u);
        acc[4] += __uint_as_float(u0.z << 16);       acc[5] += __uint_as_float(u0.z & 0xffff0000u);
        acc[6] += __uint_as_float(u0.w << 16);       acc[7] += __uint_as_float(u0.w & 0xffff0000u);
        acc[0] += __uint_as_float(u1.x << 16);       acc[1] += __uint_as_float(u1.x & 0xffff0000u);
        acc[2] += __uint_as_float(u1.y << 16);       acc[3] += __uint_as_float(u1.y & 0xffff0000u);
        acc[4] += __uint_as_float(u1.z << 16);       acc[5] += __uint_as_float(u1.z & 0xffff0000u);
        acc[6] += __uint_as_float(u1.w << 16);       acc[7] += __uint_as_float(u1.w & 0xffff0000u);
    }
    if (k < bd.y) {
        int s0 = csr_src[bd.x + k];
        uint4 u0 = *(const uint4*)(base + (long)s0 * 8);
        acc[0] += __uint_as_float(u0.x << 16);       acc[1] += __uint_as_float(u0.x & 0xffff0000u);
        acc[2] += __uint_as_float(u0.y << 16);       acc[3] += __uint_as_float(u0.y & 0xffff0000u);
        acc[4] += __uint_as_float(u0.z << 16);       acc[5] += __uint_as_float(u0.z & 0xffff0000u);
        acc[6] += __uint_as_float(u0.w << 16);       acc[7] += __uint_as_float(u0.w & 0xffff0000u);
    }
    float inv = (bd.y > 0) ? 1.f / (float)bd.y : 0.f;
    uint4 o;
    o.x = pack2bf(acc[0] * inv, acc[1] * inv);
    o.y = pack2bf(acc[2] * inv, acc[3] * inv);
    o.z = pack2bf(acc[4] * inv, acc[5] * inv);
    o.w = pack2bf(acc[6] * inv, acc[7] * inv);
    *(uint4*)(meang + i * 64 + s * 8) = o;
}

// ---------------- MFMA MLP (K=256, slice-major A): h = relu([mean|x]@W1 + b1) ----------------
template<int NOUT, bool OUT_BF16>
__global__ __launch_bounds__(256) void mfma_mlp_kernel(
        const ushort_t* __restrict__ Am, const ushort_t* __restrict__ Ax,
        const ushort_t* __restrict__ pack, const float* __restrict__ bias,
        void* __restrict__ outv) {
    constexpr int NT = NOUT / 16;
    int lane = threadIdx.x & 63;
    int wave = threadIdx.x >> 6;
    long m0 = (long)blockIdx.x * 64 + wave * 16;
    int r = lane & 15;
    int quad = lane >> 4;
    long arow = m0 + r;
    if (arow > N_NODES - 1) arow = N_NODES - 1;

    bf16x8 areg[8];
    #pragma unroll
    for (int kt = 0; kt < 8; ++kt) {
        const ushort_t* sp = (kt < 4) ? Am : Ax;
        int ktt = kt & 3;
        int slice = 2 * ktt + (quad >> 1);       // dims [ktt*32+quad*8, +8) live in slice d0/16
        areg[kt] = *(const bf16x8*)(sp + ((long)slice * N_NODES + arow) * 16 + (quad & 1) * 8);
    }

    f32x4 acc[NT];
    #pragma unroll
    for (int nt = 0; nt < NT; ++nt) acc[nt] = (f32x4){0.f, 0.f, 0.f, 0.f};

    #pragma unroll
    for (int nt = 0; nt < NT; ++nt) {
        #pragma unroll
        for (int kt = 0; kt < 8; ++kt) {
            bf16x8 bfrag = *(const bf16x8*)(pack + ((long)(nt * 8 + kt) * 64 + lane) * 8);
            acc[nt] = __builtin_amdgcn_mfma_f32_16x16x32_bf16(areg[kt], bfrag, acc[nt], 0, 0, 0);
        }
    }

    #pragma unroll
    for (int nt = 0; nt < NT; ++nt) {
        int col = nt * 16 + r;
        float bj = bias[col];
        #pragma unroll
        for (int q = 0; q < 4; ++q) {
            long orow = m0 + quad * 4 + q;
            if (orow < N_NODES) {
                float v = fmaxf(acc[nt][q] + bj, 0.f);
                if (OUT_BF16) ((ushort_t*)outv)[orow * NOUT + col] = f2bf(v);
                else          ((float*)outv)[orow * NOUT + col] = v;
            }
        }
    }
}

// ---------------- MFMA GEMM (K=128, row-major A) ----------------
// SLICE_OUT: write bf16 to slice-major-64 g. PRELOAD: C preloaded from row-major bf16.
template<int NOUT, int OUTMODE /*0=f32 row, 1=bf16 slice64*/, bool PRELOAD, bool HASBIAS, bool RELU>
__global__ __launch_bounds__(256) void mfma_gemm_k128_kernel(
        const ushort_t* __restrict__ A, const ushort_t* __restrict__ pack,
        const float* __restrict__ bias, const ushort_t* __restrict__ Cpre,
        void* __restrict__ outv) {
    constexpr int NT = NOUT / 16;
    int lane = threadIdx.x & 63;
    int wave = threadIdx.x >> 6;
    long m0 = (long)blockIdx.x * 64 + wave * 16;
    int r = lane & 15;
    int quad = lane >> 4;
    long arow = m0 + r;
    if (arow > N_NODES - 1) arow = N_NODES - 1;

    bf16x8 areg[4];
    #pragma unroll
    for (int kt = 0; kt < 4; ++kt)
        areg[kt] = *(const bf16x8*)(A + arow * 128 + kt * 32 + quad * 8);

    f32x4 acc[NT];
    #pragma unroll
    for (int nt = 0; nt < NT; ++nt) {
        if (PRELOAD) {
            int col = nt * 16 + r;
            #pragma unroll
            for (int q = 0; q < 4; ++q) {
                long row = m0 + quad * 4 + q;
                if (row > N_NODES - 1) row = N_NODES - 1;
                acc[nt][q] = bf2f(Cpre[row * NOUT + col]);
            }
        } else {
            acc[nt] = (f32x4){0.f, 0.f, 0.f, 0.f};
        }
    }

    #pragma unroll
    for (int nt = 0; nt < NT; ++nt) {
        #pragma unroll
        for (int kt = 0; kt < 4; ++kt) {
            bf16x8 bfrag = *(const bf16x8*)(pack + ((long)(nt * 4 + kt) * 64 + lane) * 8);
            acc[nt] = __builtin_amdgcn_mfma_f32_16x16x32_bf16(areg[kt], bfrag, acc[nt], 0, 0, 0);
        }
    }

    #pragma unroll
    for (int nt = 0; nt < NT; ++nt) {
        int col = nt * 16 + r;
        float bj = HASBIAS ? bias[col] : 0.f;
        #pragma unroll
        for (int q = 0; q < 4; ++q) {
            long orow = m0 + quad * 4 + q;
            if (orow < N_NODES) {
                float v = acc[nt][q] + bj;
                if (RELU) v = fmaxf(v, 0.f);
                if (OUTMODE == 1) {
                    ((ushort_t*)outv)[((long)(col >> 3) * N_NODES + orow) * 8 + (col & 7)] = f2bf(v);
                } else {
                    ((float*)outv)[orow * NOUT + col] = v;
                }
            }
        }
    }
}

extern "C" void kernel_launch(void* const* d_in, const int* in_sizes, int n_in,
                              void* d_out, int out_size, void* d_ws, size_t ws_size,
                              hipStream_t stream) {
    const float* x    = (const float*)d_in[0];
    const int*   ei   = (const int*)d_in[1];
    const float* W1_l = (const float*)d_in[2];
    const float* W1_r = (const float*)d_in[3];
    const float* b1   = (const float*)d_in[4];
    const float* W2_l = (const float*)d_in[5];
    const float* W2_r = (const float*)d_in[6];
    const float* b2   = (const float*)d_in[7];
    float* out = (float*)d_out;

    const int* src = ei;
    const int* dst = ei + N_EDGES;

    // workspace layout (16B aligned). g/meang alias mean1's 25.6 MB region.
    int*  gCur   = (int*)d_ws;                        // 512
    int2* off2   = (int2*)(gCur + 512);               // 100608 int2
    int*  bedges = (int*)(off2 + 100608);             // NB*CAP
    int*  csr    = bedges + NB * CAP;                 // NB*CAP
    ushort_t* xs    = (ushort_t*)(csr + NB * CAP);    // 25.6 MB slice-major [8][N][16]
    ushort_t* mean1 = xs + (long)N_NODES * 128;       // 25.6 MB slice-major [8][N][16]
    ushort_t* gs    = mean1;                          // alias: 12.8 MB slice-major [8][N][8]
    ushort_t* meang = mean1 + (long)N_NODES * 64;     // alias upper half: row-major [N][64]
    ushort_t* hb    = mean1 + (long)N_NODES * 128;    // 25.6 MB row-major [N][128]
    ushort_t* pack1  = hb + (long)N_NODES * 128;      // 256*128 bf16
    ushort_t* pack2l = pack1 + 256 * 128;             // 128*64
    ushort_t* pack2r = pack2l + 128 * 64;             // 128*64

    // ---- CSR build (fixed-stride buckets) ----
    init_cursor_kernel<<<2, 256, 0, stream>>>(gCur);
    bucket_scatter_kernel<<<PART_BLOCKS, 256, 0, stream>>>(src, dst, gCur, bedges);
    bucket_sort_kernel<<<NB, 256, 0, stream>>>(gCur, bedges, csr, off2);

    // ---- precision prep ----
    cvt_slice_kernel<<<(N_NODES + 31) / 32, 256, 0, stream>>>(x, xs);
    pack_w_kernel<<<((128 / 16) * 8 * 64 + 255) / 256, 256, 0, stream>>>(W1_l, W1_r, pack1, 128);
    pack_wk128_kernel<<<((64 / 16) * 4 * 64 + 255) / 256, 256, 0, stream>>>(W2_l, pack2l, 64);
    pack_wk128_kernel<<<((64 / 16) * 4 * 64 + 255) / 256, 256, 0, stream>>>(W2_r, pack2r, 64);

    // ---- layer 1: mean1 = gather(x) [sliced]; h = relu([mean1|x]@W1 + b1) ----
    gather_slice128_kernel<<<((N_NODES + 127) / 128) * 8, 256, 0, stream>>>(off2, csr, xs, mean1);
    mfma_mlp_kernel<128, true><<<(N_NODES + 63) / 64, 256, 0, stream>>>(mean1, xs, pack1, b1, hb);

    // ---- layer 2: g = h@W2_l [slice64 out]; meang = gather(g) [sliced];
    //      out = relu(meang + h@W2_r + b2) ----
    mfma_gemm_k128_kernel<64, 1, false, false, false><<<(N_NODES + 63) / 64, 256, 0, stream>>>(
        hb, pack2l, nullptr, nullptr, gs);
    gather_slice64_kernel<<<((N_NODES + 255) / 256) * 8, 256, 0, stream>>>(off2, csr, gs, meang);
    mfma_gemm_k128_kernel<64, 0, true, true, true><<<(N_NODES + 63) / 64, 256, 0, stream>>>(
        hb, pack2r, b2, meang, out);
}

// Round 8
// 301.936 us; speedup vs baseline: 1.3573x; 1.3573x over previous
//
#include <hip/hip_runtime.h>

#define N_NODES 100000
#define N_EDGES 1600000
#define D_IN 128
#define D_HID 128
#define D_LAT 64

#define BSHIFT 8                          // 256 nodes per bucket
#define NB 392                            // ceil(100352 / 256) buckets
#define CAP 4608                          // slots per bucket region (mean 4082 + 8.2 sigma)
#define EPB 4096                          // edges per partition block
#define PART_BLOCKS ((N_EDGES + EPB - 1) / EPB)   // 391

typedef unsigned short ushort_t;
typedef unsigned int uint_t;
using bf16x8 = __attribute__((ext_vector_type(8))) short;
using f32x4  = __attribute__((ext_vector_type(4))) float;

__device__ inline ushort_t f2bf(float f) {
    uint_t u = __float_as_uint(f);
    return (ushort_t)((u + 0x7fffu + ((u >> 16) & 1u)) >> 16);   // RNE
}
__device__ inline uint_t pack2bf(float a, float b) {
    return (uint_t)f2bf(a) | ((uint_t)f2bf(b) << 16);
}
__device__ inline float bf2f(ushort_t u) {
    return __uint_as_float(((uint_t)u) << 16);
}
__device__ inline void acc8(float* acc, uint4 u) {
    acc[0] += __uint_as_float(u.x << 16);
    acc[1] += __uint_as_float(u.x & 0xffff0000u);
    acc[2] += __uint_as_float(u.y << 16);
    acc[3] += __uint_as_float(u.y & 0xffff0000u);
    acc[4] += __uint_as_float(u.z << 16);
    acc[5] += __uint_as_float(u.z & 0xffff0000u);
    acc[6] += __uint_as_float(u.w << 16);
    acc[7] += __uint_as_float(u.w & 0xffff0000u);
}

// ---------------- CSR build: fixed-stride bucketed counting sort ----------------
__global__ void init_cursor_kernel(int* __restrict__ gCur) {
    int t = blockIdx.x * blockDim.x + threadIdx.x;
    if (t < NB) gCur[t] = t * CAP;
}

__global__ __launch_bounds__(256) void bucket_scatter_kernel(const int* __restrict__ src,
                                                             const int* __restrict__ dst,
                                                             int* __restrict__ gCur,
                                                             int* __restrict__ bedges) {
    __shared__ int h[NB];
    __shared__ int start[NB];
    for (int j = threadIdx.x; j < NB; j += 256) h[j] = 0;
    __syncthreads();
    long base = (long)blockIdx.x * EPB;
    #pragma unroll
    for (int i = 0; i < EPB / 256; ++i) {
        long e = base + i * 256 + threadIdx.x;
        if (e < N_EDGES) atomicAdd(&h[dst[e] >> BSHIFT], 1);
    }
    __syncthreads();
    for (int j = threadIdx.x; j < NB; j += 256)
        start[j] = h[j] ? atomicAdd(&gCur[j], h[j]) : 0;
    __syncthreads();
    #pragma unroll
    for (int i = 0; i < EPB / 256; ++i) {
        long e = base + i * 256 + threadIdx.x;
        if (e < N_EDGES) {
            int d = dst[e];
            int b = d >> BSHIFT;
            int p = atomicAdd(&start[b], 1);
            if (p < (b + 1) * CAP)                     // overflow clamp (P ~ 1e-16)
                bedges[p] = ((d & 255) << 24) | src[e];
        }
    }
}

__global__ __launch_bounds__(256) void bucket_sort_kernel(const int* __restrict__ gCur,
                                                          const int* __restrict__ bedges,
                                                          int* __restrict__ csr,
                                                          int2* __restrict__ off2) {
    __shared__ int sdata[256];
    __shared__ int cur[256];
    int b = blockIdx.x, t = threadIdx.x;
    int r0 = b * CAP;
    int n = gCur[b] - r0;
    if (n > CAP) n = CAP;
    cur[t] = 0;
    __syncthreads();
    for (int k = t; k < n; k += 256) atomicAdd(&cur[(unsigned)bedges[r0 + k] >> 24], 1);
    __syncthreads();
    int c = cur[t];
    sdata[t] = c;
    __syncthreads();
    for (int d = 1; d < 256; d <<= 1) {
        int u = (t >= d) ? sdata[t - d] : 0;
        __syncthreads();
        sdata[t] += u;
        __syncthreads();
    }
    int ex = (t == 0) ? 0 : sdata[t - 1];
    off2[(b << BSHIFT) + t] = make_int2(r0 + ex, c);
    cur[t] = ex;
    __syncthreads();
    for (int k = t; k < n; k += 256) {
        int v = bedges[r0 + k];
        int p = atomicAdd(&cur[(unsigned)v >> 24], 1);
        csr[r0 + p] = v & 0xFFFFFF;
    }
}

// ---------------- fp32 -> bf16 conversion (8 elems/thread) ----------------
__global__ void cvt_bf16_kernel(const float* __restrict__ in, ushort_t* __restrict__ out, long n) {
    long i = ((long)blockIdx.x * blockDim.x + threadIdx.x) * 8;
    if (i >= n) return;
    float4 a = *(const float4*)(in + i);
    float4 b = *(const float4*)(in + i + 4);
    uint4 o;
    o.x = pack2bf(a.x, a.y);
    o.y = pack2bf(a.z, a.w);
    o.z = pack2bf(b.x, b.y);
    o.w = pack2bf(b.z, b.w);
    *(uint4*)(out + i) = o;
}

// ---------------- pack [Wl;Wr] (K=256 x N) into MFMA B-fragment order ----------------
__global__ void pack_w_kernel(const float* __restrict__ Wl, const float* __restrict__ Wr,
                              ushort_t* __restrict__ pack, int N) {
    int tid = blockIdx.x * blockDim.x + threadIdx.x;
    int total = (N / 16) * 8 * 64;
    if (tid >= total) return;
    int lane = tid & 63;
    int t = tid >> 6;
    int kt = t & 7;
    int nt = t >> 3;
    int n = nt * 16 + (lane & 15);
    int kbase = kt * 32 + (lane >> 4) * 8;
    ushort_t v[8];
    #pragma unroll
    for (int j = 0; j < 8; ++j) {
        int k = kbase + j;
        float w = (k < 128) ? Wl[k * N + n] : Wr[(k - 128) * N + n];
        v[j] = f2bf(w);
    }
    *(uint4*)(pack + (long)tid * 8) = *(uint4*)v;
}

__global__ void pack_wk128_kernel(const float* __restrict__ W, ushort_t* __restrict__ pack, int N) {
    int tid = blockIdx.x * blockDim.x + threadIdx.x;
    int total = (N / 16) * 4 * 64;
    if (tid >= total) return;
    int lane = tid & 63;
    int t = tid >> 6;
    int kt = t & 3;
    int nt = t >> 2;
    int n = nt * 16 + (lane & 15);
    int kbase = kt * 32 + (lane >> 4) * 8;
    ushort_t v[8];
    #pragma unroll
    for (int j = 0; j < 8; ++j) v[j] = f2bf(W[(kbase + j) * N + n]);
    *(uint4*)(pack + (long)tid * 8) = *(uint4*)v;
}

// ---------------- gather-mean 128-dim, 4-edge software pipeline ----------------
__global__ __launch_bounds__(256) void gather_mean_kernel(
        const int2* __restrict__ off2, const int* __restrict__ csr_src,
        const ushort_t* __restrict__ feat, ushort_t* __restrict__ mean_out) {
    int lane  = threadIdx.x & 15;
    int local = threadIdx.x >> 4;
    long i = (long)blockIdx.x * 16 + local;
    if (i >= N_NODES) return;
    int2 bd = off2[i];
    int beg = bd.x, n = bd.y;
    const ushort_t* base = feat + lane * 8;
    float acc[8] = {0.f, 0.f, 0.f, 0.f, 0.f, 0.f, 0.f, 0.f};
    int k = 0;
    for (; k + 4 <= n; k += 4) {
        int s0 = csr_src[beg + k];
        int s1 = csr_src[beg + k + 1];
        int s2 = csr_src[beg + k + 2];
        int s3 = csr_src[beg + k + 3];
        uint4 u0 = *(const uint4*)(base + (long)s0 * 128);
        uint4 u1 = *(const uint4*)(base + (long)s1 * 128);
        uint4 u2 = *(const uint4*)(base + (long)s2 * 128);
        uint4 u3 = *(const uint4*)(base + (long)s3 * 128);
        acc8(acc, u0); acc8(acc, u1); acc8(acc, u2); acc8(acc, u3);
    }
    for (; k < n; ++k) {
        int s0 = csr_src[beg + k];
        uint4 u0 = *(const uint4*)(base + (long)s0 * 128);
        acc8(acc, u0);
    }
    float inv = (n > 0) ? 1.f / (float)n : 0.f;
    uint4 o;
    o.x = pack2bf(acc[0] * inv, acc[1] * inv);
    o.y = pack2bf(acc[2] * inv, acc[3] * inv);
    o.z = pack2bf(acc[4] * inv, acc[5] * inv);
    o.w = pack2bf(acc[6] * inv, acc[7] * inv);
    *(uint4*)(mean_out + i * 128 + lane * 8) = o;
}

// ---------------- gather-mean 64-dim, 4-edge software pipeline ----------------
__global__ __launch_bounds__(256) void gather_mean64_kernel(
        const int2* __restrict__ off2, const int* __restrict__ csr_src,
        const ushort_t* __restrict__ feat, ushort_t* __restrict__ mean_out) {
    int lane  = threadIdx.x & 7;
    int local = threadIdx.x >> 3;
    long i = (long)blockIdx.x * 32 + local;
    if (i >= N_NODES) return;
    int2 bd = off2[i];
    int beg = bd.x, n = bd.y;
    const ushort_t* base = feat + lane * 8;
    float acc[8] = {0.f, 0.f, 0.f, 0.f, 0.f, 0.f, 0.f, 0.f};
    int k = 0;
    for (; k + 4 <= n; k += 4) {
        int s0 = csr_src[beg + k];
        int s1 = csr_src[beg + k + 1];
        int s2 = csr_src[beg + k + 2];
        int s3 = csr_src[beg + k + 3];
        uint4 u0 = *(const uint4*)(base + (long)s0 * 64);
        uint4 u1 = *(const uint4*)(base + (long)s1 * 64);
        uint4 u2 = *(const uint4*)(base + (long)s2 * 64);
        uint4 u3 = *(const uint4*)(base + (long)s3 * 64);
        acc8(acc, u0); acc8(acc, u1); acc8(acc, u2); acc8(acc, u3);
    }
    for (; k < n; ++k) {
        int s0 = csr_src[beg + k];
        uint4 u0 = *(const uint4*)(base + (long)s0 * 64);
        acc8(acc, u0);
    }
    float inv = (n > 0) ? 1.f / (float)n : 0.f;
    uint4 o;
    o.x = pack2bf(acc[0] * inv, acc[1] * inv);
    o.y = pack2bf(acc[2] * inv, acc[3] * inv);
    o.z = pack2bf(acc[4] * inv, acc[5] * inv);
    o.w = pack2bf(acc[6] * inv, acc[7] * inv);
    *(uint4*)(mean_out + i * 64 + lane * 8) = o;
}

// ---------------- MFMA MLP (K=256): h = relu([mean|x]@W1 + b1) ----------------
template<int NOUT, bool OUT_BF16>
__global__ __launch_bounds__(256) void mfma_mlp_kernel(
        const ushort_t* __restrict__ Am, const ushort_t* __restrict__ Ax,
        const ushort_t* __restrict__ pack, const float* __restrict__ bias,
        void* __restrict__ outv) {
    constexpr int NT = NOUT / 16;
    int lane = threadIdx.x & 63;
    int wave = threadIdx.x >> 6;
    long m0 = (long)blockIdx.x * 64 + wave * 16;
    int r = lane & 15;
    int quad = lane >> 4;
    long arow = m0 + r;
    if (arow > N_NODES - 1) arow = N_NODES - 1;

    bf16x8 areg[8];
    #pragma unroll
    for (int kt = 0; kt < 8; ++kt) {
        const ushort_t* s = (kt < 4) ? Am : Ax;
        int k = (kt & 3) * 32 + quad * 8;
        areg[kt] = *(const bf16x8*)(s + arow * 128 + k);
    }

    f32x4 acc[NT];
    #pragma unroll
    for (int nt = 0; nt < NT; ++nt) acc[nt] = (f32x4){0.f, 0.f, 0.f, 0.f};

    #pragma unroll
    for (int nt = 0; nt < NT; ++nt) {
        #pragma unroll
        for (int kt = 0; kt < 8; ++kt) {
            bf16x8 bfrag = *(const bf16x8*)(pack + ((long)(nt * 8 + kt) * 64 + lane) * 8);
            acc[nt] = __builtin_amdgcn_mfma_f32_16x16x32_bf16(areg[kt], bfrag, acc[nt], 0, 0, 0);
        }
    }

    #pragma unroll
    for (int nt = 0; nt < NT; ++nt) {
        int col = nt * 16 + r;
        float bj = bias[col];
        #pragma unroll
        for (int q = 0; q < 4; ++q) {
            long orow = m0 + quad * 4 + q;
            if (orow < N_NODES) {
                float v = fmaxf(acc[nt][q] + bj, 0.f);
                if (OUT_BF16) ((ushort_t*)outv)[orow * NOUT + col] = f2bf(v);
                else          ((float*)outv)[orow * NOUT + col] = v;
            }
        }
    }
}

// ---------------- MFMA GEMM (K=128): out = [relu]( A @ packedW [+ Cpre] [+ b] ) ----------------
template<int NOUT, bool OUT_BF16, bool PRELOAD, bool HASBIAS, bool RELU>
__global__ __launch_bounds__(256) void mfma_gemm_k128_kernel(
        const ushort_t* __restrict__ A, const ushort_t* __restrict__ pack,
        const float* __restrict__ bias, const ushort_t* __restrict__ Cpre,
        void* __restrict__ outv) {
    constexpr int NT = NOUT / 16;
    int lane = threadIdx.x & 63;
    int wave = threadIdx.x >> 6;
    long m0 = (long)blockIdx.x * 64 + wave * 16;
    int r = lane & 15;
    int quad = lane >> 4;
    long arow = m0 + r;
    if (arow > N_NODES - 1) arow = N_NODES - 1;

    bf16x8 areg[4];
    #pragma unroll
    for (int kt = 0; kt < 4; ++kt)
        areg[kt] = *(const bf16x8*)(A + arow * 128 + kt * 32 + quad * 8);

    f32x4 acc[NT];
    #pragma unroll
    for (int nt = 0; nt < NT; ++nt) {
        if (PRELOAD) {
            int col = nt * 16 + r;
            #pragma unroll
            for (int q = 0; q < 4; ++q) {
                long row = m0 + quad * 4 + q;
                if (row > N_NODES - 1) row = N_NODES - 1;
                acc[nt][q] = bf2f(Cpre[row * NOUT + col]);
            }
        } else {
            acc[nt] = (f32x4){0.f, 0.f, 0.f, 0.f};
        }
    }

    #pragma unroll
    for (int nt = 0; nt < NT; ++nt) {
        #pragma unroll
        for (int kt = 0; kt < 4; ++kt) {
            bf16x8 bfrag = *(const bf16x8*)(pack + ((long)(nt * 4 + kt) * 64 + lane) * 8);
            acc[nt] = __builtin_amdgcn_mfma_f32_16x16x32_bf16(areg[kt], bfrag, acc[nt], 0, 0, 0);
        }
    }

    #pragma unroll
    for (int nt = 0; nt < NT; ++nt) {
        int col = nt * 16 + r;
        float bj = HASBIAS ? bias[col] : 0.f;
        #pragma unroll
        for (int q = 0; q < 4; ++q) {
            long orow = m0 + quad * 4 + q;
            if (orow < N_NODES) {
                float v = acc[nt][q] + bj;
                if (RELU) v = fmaxf(v, 0.f);
                if (OUT_BF16) ((ushort_t*)outv)[orow * NOUT + col] = f2bf(v);
                else          ((float*)outv)[orow * NOUT + col] = v;
            }
        }
    }
}

extern "C" void kernel_launch(void* const* d_in, const int* in_sizes, int n_in,
                              void* d_out, int out_size, void* d_ws, size_t ws_size,
                              hipStream_t stream) {
    const float* x    = (const float*)d_in[0];
    const int*   ei   = (const int*)d_in[1];
    const float* W1_l = (const float*)d_in[2];
    const float* W1_r = (const float*)d_in[3];
    const float* b1   = (const float*)d_in[4];
    const float* W2_l = (const float*)d_in[5];
    const float* W2_r = (const float*)d_in[6];
    const float* b2   = (const float*)d_in[7];
    float* out = (float*)d_out;

    const int* src = ei;
    const int* dst = ei + N_EDGES;

    // workspace layout (16B aligned). g/meang alias mean1's 25.6 MB region.
    int*  gCur   = (int*)d_ws;                        // 512
    int2* off2   = (int2*)(gCur + 512);               // 100608 int2
    int*  bedges = (int*)(off2 + 100608);             // NB*CAP
    int*  csr    = bedges + NB * CAP;                 // NB*CAP
    ushort_t* xb    = (ushort_t*)(csr + NB * CAP);    // 25.6 MB row-major [N][128]
    ushort_t* mean1 = xb + (long)N_NODES * 128;       // 25.6 MB region
    ushort_t* g     = mean1;                          // alias (12.8 MB, used after mean1 dead)
    ushort_t* meang = mean1 + (long)N_NODES * 64;     // alias upper half (12.8 MB)
    ushort_t* hb    = mean1 + (long)N_NODES * 128;    // 25.6 MB row-major [N][128]
    ushort_t* pack1  = hb + (long)N_NODES * 128;      // 256*128 bf16
    ushort_t* pack2l = pack1 + 256 * 128;             // 128*64
    ushort_t* pack2r = pack2l + 128 * 64;             // 128*64

    // ---- CSR build (fixed-stride buckets) ----
    init_cursor_kernel<<<2, 256, 0, stream>>>(gCur);
    bucket_scatter_kernel<<<PART_BLOCKS, 256, 0, stream>>>(src, dst, gCur, bedges);
    bucket_sort_kernel<<<NB, 256, 0, stream>>>(gCur, bedges, csr, off2);

    // ---- precision prep ----
    cvt_bf16_kernel<<<((long)N_NODES * 128 / 8 + 255) / 256, 256, 0, stream>>>(
        x, xb, (long)N_NODES * 128);
    pack_w_kernel<<<((128 / 16) * 8 * 64 + 255) / 256, 256, 0, stream>>>(W1_l, W1_r, pack1, 128);
    pack_wk128_kernel<<<((64 / 16) * 4 * 64 + 255) / 256, 256, 0, stream>>>(W2_l, pack2l, 64);
    pack_wk128_kernel<<<((64 / 16) * 4 * 64 + 255) / 256, 256, 0, stream>>>(W2_r, pack2r, 64);

    // ---- layer 1: mean1 = gather(x); h = relu([mean1|x]@W1 + b1) ----
    gather_mean_kernel<<<(N_NODES + 15) / 16, 256, 0, stream>>>(off2, csr, xb, mean1);
    mfma_mlp_kernel<128, true><<<(N_NODES + 63) / 64, 256, 0, stream>>>(mean1, xb, pack1, b1, hb);

    // ---- layer 2: g = h@W2_l; meang = gather(g); out = relu(meang + h@W2_r + b2) ----
    mfma_gemm_k128_kernel<64, true, false, false, false><<<(N_NODES + 63) / 64, 256, 0, stream>>>(
        hb, pack2l, nullptr, nullptr, g);
    gather_mean64_kernel<<<(N_NODES + 31) / 32, 256, 0, stream>>>(off2, csr, g, meang);
    mfma_gemm_k128_kernel<64, false, true, true, true><<<(N_NODES + 63) / 64, 256, 0, stream>>>(
        hb, pack2r, b2, meang, out);
}

// Round 10
// 282.845 us; speedup vs baseline: 1.4489x; 1.0675x over previous
//
#include <hip/hip_runtime.h>

#define N_NODES 100000
#define N_EDGES 1600000
#define D_IN 128
#define D_HID 128
#define D_LAT 64

#define BSHIFT 8                          // 256 nodes per bucket
#define NB 392                            // ceil(100352 / 256) buckets
#define CAP 4608                          // slots per bucket region (mean 4082 + 8.2 sigma)
#define EPB 4096                          // edges per partition block
#define NPT (EPB / 256)                   // 16 edges per thread
#define PART_BLOCKS ((N_EDGES + EPB - 1) / EPB)   // 391

typedef unsigned short ushort_t;
typedef unsigned int uint_t;
typedef unsigned char uchar_t;
using bf16x8 = __attribute__((ext_vector_type(8))) short;
using f32x4  = __attribute__((ext_vector_type(4))) float;
using f32x2  = __attribute__((ext_vector_type(2))) float;

__device__ inline ushort_t f2bf(float f) {
    uint_t u = __float_as_uint(f);
    return (ushort_t)((u + 0x7fffu + ((u >> 16) & 1u)) >> 16);   // RNE
}
__device__ inline uint_t pack2bf(float a, float b) {
    return (uint_t)f2bf(a) | ((uint_t)f2bf(b) << 16);
}
__device__ inline float bf2f(ushort_t u) {
    return __uint_as_float(((uint_t)u) << 16);
}
__device__ inline void acc8(float* acc, uint4 u) {
    acc[0] += __uint_as_float(u.x << 16);
    acc[1] += __uint_as_float(u.x & 0xffff0000u);
    acc[2] += __uint_as_float(u.y << 16);
    acc[3] += __uint_as_float(u.y & 0xffff0000u);
    acc[4] += __uint_as_float(u.z << 16);
    acc[5] += __uint_as_float(u.z & 0xffff0000u);
    acc[6] += __uint_as_float(u.w << 16);
    acc[7] += __uint_as_float(u.w & 0xffff0000u);
}

// ---------------- fp8 e4m3 helpers (word-select must be compile-time) ----------------
#if __has_builtin(__builtin_amdgcn_cvt_pk_f32_fp8) && __has_builtin(__builtin_amdgcn_cvt_pk_fp8_f32)
template<bool HI>
__device__ inline f32x2 fp8pk2f(uint_t v) {
    return __builtin_amdgcn_cvt_pk_f32_fp8(v, HI);       // HI is an ICE here
}
__device__ inline uint_t f2fp8pk4(float a, float b, float c, float d) {
    uint_t w = __builtin_amdgcn_cvt_pk_fp8_f32(a, b, 0, false);
    w = __builtin_amdgcn_cvt_pk_fp8_f32(c, d, w, true);
    return w;
}
#else
// fallback: software e4m3fn (normals exact w/ RNE; subnormals flushed)
__device__ inline float fp8b2f(uint_t b) {
    uint_t em = b & 0x7f;
    if (em == 0) return 0.f;
    uint_t bits = ((em << 20) + (120u << 23)) | ((b & 0x80u) << 24);
    return __uint_as_float(bits);
}
template<bool HI>
__device__ inline f32x2 fp8pk2f(uint_t v) {
    uint_t w = HI ? (v >> 16) : v;
    f32x2 r; r.x = fp8b2f(w & 0xff); r.y = fp8b2f((w >> 8) & 0xff);
    return r;
}
__device__ inline uint_t f2fp8_1(float f) {
    uint_t u = __float_as_uint(f);
    uint_t s = (u >> 31) << 7;
    uint_t au = u & 0x7fffffff;
    if (au >= 0x43e00000u) return s | 0x7e;              // clamp to 448
    if (au < 0x3c000000u) return s;                      // < 2^-7 -> 0 (approx)
    uint_t r = au + 0x0007ffffu + ((au >> 20) & 1u);     // RNE at 3 mantissa bits
    return s | (((r >> 20) - (120u << 3)) & 0x7f);
}
__device__ inline uint_t f2fp8pk4(float a, float b, float c, float d) {
    return f2fp8_1(a) | (f2fp8_1(b) << 8) | (f2fp8_1(c) << 16) | (f2fp8_1(d) << 24);
}
#endif

__device__ inline void accf8x4(float* a, uint_t w, int base) {
    f32x2 p0 = fp8pk2f<false>(w);
    f32x2 p1 = fp8pk2f<true>(w);
    a[base + 0] += p0.x; a[base + 1] += p0.y;
    a[base + 2] += p1.x; a[base + 3] += p1.y;
}
__device__ inline void accf8x16(float* a, uint4 u) {
    accf8x4(a, u.x, 0); accf8x4(a, u.y, 4); accf8x4(a, u.z, 8); accf8x4(a, u.w, 12);
}

// ---------------- CSR build: fixed-stride bucketed counting sort ----------------
__global__ void init_cursor_kernel(int* __restrict__ gCur) {
    int t = blockIdx.x * blockDim.x + threadIdx.x;
    if (t < NB) gCur[t] = t * CAP;
}

__global__ __launch_bounds__(256) void bucket_scatter_kernel(const int* __restrict__ src,
                                                             const int* __restrict__ dst,
                                                             int* __restrict__ gCur,
                                                             int* __restrict__ bedges) {
    __shared__ int h[NB];
    __shared__ int start[NB];
    for (int j = threadIdx.x; j < NB; j += 256) h[j] = 0;
    __syncthreads();
    long base = (long)blockIdx.x * EPB;
    int dc[NPT], sc[NPT];
    #pragma unroll
    for (int i = 0; i < NPT; ++i) {
        long e = base + i * 256 + threadIdx.x;
        bool v = (e < N_EDGES);
        dc[i] = v ? dst[e] : -1;
        sc[i] = v ? src[e] : 0;
        if (v) atomicAdd(&h[dc[i] >> BSHIFT], 1);
    }
    __syncthreads();
    for (int j = threadIdx.x; j < NB; j += 256)
        start[j] = h[j] ? atomicAdd(&gCur[j], h[j]) : 0;
    __syncthreads();
    #pragma unroll
    for (int i = 0; i < NPT; ++i) {
        if (dc[i] >= 0) {
            int b = dc[i] >> BSHIFT;
            int p = atomicAdd(&start[b], 1);
            if (p < (b + 1) * CAP)                     // overflow clamp (P ~ 1e-16)
                bedges[p] = ((dc[i] & 255) << 24) | sc[i];
        }
    }
}

__global__ __launch_bounds__(256) void bucket_sort_kernel(const int* __restrict__ gCur,
                                                          const int* __restrict__ bedges,
                                                          int* __restrict__ csr,
                                                          int2* __restrict__ off2) {
    __shared__ int sdata[256];
    __shared__ int cur[256];
    int b = blockIdx.x, t = threadIdx.x;
    int r0 = b * CAP;
    int n = gCur[b] - r0;
    if (n > CAP) n = CAP;
    cur[t] = 0;
    __syncthreads();
    for (int k = t; k < n; k += 256) atomicAdd(&cur[(unsigned)bedges[r0 + k] >> 24], 1);
    __syncthreads();
    int c = cur[t];
    sdata[t] = c;
    __syncthreads();
    for (int d = 1; d < 256; d <<= 1) {
        int u = (t >= d) ? sdata[t - d] : 0;
        __syncthreads();
        sdata[t] += u;
        __syncthreads();
    }
    int ex = (t == 0) ? 0 : sdata[t - 1];
    off2[(b << BSHIFT) + t] = make_int2(r0 + ex, c);
    cur[t] = ex;
    __syncthreads();
    for (int k = t; k < n; k += 256) {
        int v = bedges[r0 + k];
        int p = atomicAdd(&cur[(unsigned)v >> 24], 1);
        csr[r0 + p] = v & 0xFFFFFF;
    }
}

// ---------------- fp32 -> bf16 conversion (8 elems/thread) ----------------
__global__ void cvt_bf16_kernel(const float* __restrict__ in, ushort_t* __restrict__ out, long n) {
    long i = ((long)blockIdx.x * blockDim.x + threadIdx.x) * 8;
    if (i >= n) return;
    float4 a = *(const float4*)(in + i);
    float4 b = *(const float4*)(in + i + 4);
    uint4 o;
    o.x = pack2bf(a.x, a.y);
    o.y = pack2bf(a.z, a.w);
    o.z = pack2bf(b.x, b.y);
    o.w = pack2bf(b.z, b.w);
    *(uint4*)(out + i) = o;
}

// ---------------- fp32 -> fp8 conversion (8 elems/thread) ----------------
__global__ void cvt_fp8_kernel(const float* __restrict__ in, uchar_t* __restrict__ out, long n) {
    long i = ((long)blockIdx.x * blockDim.x + threadIdx.x) * 8;
    if (i >= n) return;
    float4 a = *(const float4*)(in + i);
    float4 b = *(const float4*)(in + i + 4);
    uint2 o;
    o.x = f2fp8pk4(a.x, a.y, a.z, a.w);
    o.y = f2fp8pk4(b.x, b.y, b.z, b.w);
    *(uint2*)(out + i) = o;
}

// ---------------- pack [Wl;Wr] (K=256 x N) into MFMA B-fragment order ----------------
__global__ void pack_w_kernel(const float* __restrict__ Wl, const float* __restrict__ Wr,
                              ushort_t* __restrict__ pack, int N) {
    int tid = blockIdx.x * blockDim.x + threadIdx.x;
    int total = (N / 16) * 8 * 64;
    if (tid >= total) return;
    int lane = tid & 63;
    int t = tid >> 6;
    int kt = t & 7;
    int nt = t >> 3;
    int n = nt * 16 + (lane & 15);
    int kbase = kt * 32 + (lane >> 4) * 8;
    ushort_t v[8];
    #pragma unroll
    for (int j = 0; j < 8; ++j) {
        int k = kbase + j;
        float w = (k < 128) ? Wl[k * N + n] : Wr[(k - 128) * N + n];
        v[j] = f2bf(w);
    }
    *(uint4*)(pack + (long)tid * 8) = *(uint4*)v;
}

__global__ void pack_wk128_kernel(const float* __restrict__ W, ushort_t* __restrict__ pack, int N) {
    int tid = blockIdx.x * blockDim.x + threadIdx.x;
    int total = (N / 16) * 4 * 64;
    if (tid >= total) return;
    int lane = tid & 63;
    int t = tid >> 6;
    int kt = t & 3;
    int nt = t >> 2;
    int n = nt * 16 + (lane & 15);
    int kbase = kt * 32 + (lane >> 4) * 8;
    ushort_t v[8];
    #pragma unroll
    for (int j = 0; j < 8; ++j) v[j] = f2bf(W[(kbase + j) * N + n]);
    *(uint4*)(pack + (long)tid * 8) = *(uint4*)v;
}

// ---------------- gather-mean 128-dim fp8, 4-edge pipeline ----------------
// 8 lanes per node (16 dims / 16 B each), 32 nodes per 256-thread block.
__global__ __launch_bounds__(256) void gather_mean_fp8_kernel(
        const int2* __restrict__ off2, const int* __restrict__ csr_src,
        const uchar_t* __restrict__ x8, ushort_t* __restrict__ mean_out) {
    int lane  = threadIdx.x & 7;
    int local = threadIdx.x >> 3;
    long i = (long)blockIdx.x * 32 + local;
    if (i >= N_NODES) return;
    int2 bd = off2[i];
    int beg = bd.x, n = bd.y;
    const uchar_t* base = x8 + lane * 16;
    float acc[16];
    #pragma unroll
    for (int j = 0; j < 16; ++j) acc[j] = 0.f;
    int k = 0;
    for (; k + 4 <= n; k += 4) {
        int s0 = csr_src[beg + k];
        int s1 = csr_src[beg + k + 1];
        int s2 = csr_src[beg + k + 2];
        int s3 = csr_src[beg + k + 3];
        uint4 u0 = *(const uint4*)(base + (long)s0 * 128);
        uint4 u1 = *(const uint4*)(base + (long)s1 * 128);
        uint4 u2 = *(const uint4*)(base + (long)s2 * 128);
        uint4 u3 = *(const uint4*)(base + (long)s3 * 128);
        accf8x16(acc, u0); accf8x16(acc, u1); accf8x16(acc, u2); accf8x16(acc, u3);
    }
    for (; k < n; ++k) {
        int s0 = csr_src[beg + k];
        uint4 u0 = *(const uint4*)(base + (long)s0 * 128);
        accf8x16(acc, u0);
    }
    float inv = (n > 0) ? 1.f / (float)n : 0.f;
    uint4 o0, o1;
    o0.x = pack2bf(acc[0] * inv,  acc[1] * inv);
    o0.y = pack2bf(acc[2] * inv,  acc[3] * inv);
    o0.z = pack2bf(acc[4] * inv,  acc[5] * inv);
    o0.w = pack2bf(acc[6] * inv,  acc[7] * inv);
    o1.x = pack2bf(acc[8] * inv,  acc[9] * inv);
    o1.y = pack2bf(acc[10] * inv, acc[11] * inv);
    o1.z = pack2bf(acc[12] * inv, acc[13] * inv);
    o1.w = pack2bf(acc[14] * inv, acc[15] * inv);
    ushort_t* mp = mean_out + i * 128 + lane * 16;
    *(uint4*)mp = o0;
    *(uint4*)(mp + 8) = o1;
}

// ---------------- gather-mean 64-dim bf16, 4-edge pipeline ----------------
__global__ __launch_bounds__(256) void gather_mean64_kernel(
        const int2* __restrict__ off2, const int* __restrict__ csr_src,
        const ushort_t* __restrict__ feat, ushort_t* __restrict__ mean_out) {
    int lane  = threadIdx.x & 7;
    int local = threadIdx.x >> 3;
    long i = (long)blockIdx.x * 32 + local;
    if (i >= N_NODES) return;
    int2 bd = off2[i];
    int beg = bd.x, n = bd.y;
    const ushort_t* base = feat + lane * 8;
    float acc[8] = {0.f, 0.f, 0.f, 0.f, 0.f, 0.f, 0.f, 0.f};
    int k = 0;
    for (; k + 4 <= n; k += 4) {
        int s0 = csr_src[beg + k];
        int s1 = csr_src[beg + k + 1];
        int s2 = csr_src[beg + k + 2];
        int s3 = csr_src[beg + k + 3];
        uint4 u0 = *(const uint4*)(base + (long)s0 * 64);
        uint4 u1 = *(const uint4*)(base + (long)s1 * 64);
        uint4 u2 = *(const uint4*)(base + (long)s2 * 64);
        uint4 u3 = *(const uint4*)(base + (long)s3 * 64);
        acc8(acc, u0); acc8(acc, u1); acc8(acc, u2); acc8(acc, u3);
    }
    for (; k < n; ++k) {
        int s0 = csr_src[beg + k];
        uint4 u0 = *(const uint4*)(base + (long)s0 * 64);
        acc8(acc, u0);
    }
    float inv = (n > 0) ? 1.f / (float)n : 0.f;
    uint4 o;
    o.x = pack2bf(acc[0] * inv, acc[1] * inv);
    o.y = pack2bf(acc[2] * inv, acc[3] * inv);
    o.z = pack2bf(acc[4] * inv, acc[5] * inv);
    o.w = pack2bf(acc[6] * inv, acc[7] * inv);
    *(uint4*)(mean_out + i * 64 + lane * 8) = o;
}

// ---------------- MFMA MLP (K=256): h = relu([mean|x]@W1 + b1) ----------------
template<int NOUT, bool OUT_BF16>
__global__ __launch_bounds__(256) void mfma_mlp_kernel(
        const ushort_t* __restrict__ Am, const ushort_t* __restrict__ Ax,
        const ushort_t* __restrict__ pack, const float* __restrict__ bias,
        void* __restrict__ outv) {
    constexpr int NT = NOUT / 16;
    int lane = threadIdx.x & 63;
    int wave = threadIdx.x >> 6;
    long m0 = (long)blockIdx.x * 64 + wave * 16;
    int r = lane & 15;
    int quad = lane >> 4;
    long arow = m0 + r;
    if (arow > N_NODES - 1) arow = N_NODES - 1;

    bf16x8 areg[8];
    #pragma unroll
    for (int kt = 0; kt < 8; ++kt) {
        const ushort_t* s = (kt < 4) ? Am : Ax;
        int k = (kt & 3) * 32 + quad * 8;
        areg[kt] = *(const bf16x8*)(s + arow * 128 + k);
    }

    f32x4 acc[NT];
    #pragma unroll
    for (int nt = 0; nt < NT; ++nt) acc[nt] = (f32x4){0.f, 0.f, 0.f, 0.f};

    #pragma unroll
    for (int nt = 0; nt < NT; ++nt) {
        #pragma unroll
        for (int kt = 0; kt < 8; ++kt) {
            bf16x8 bfrag = *(const bf16x8*)(pack + ((long)(nt * 8 + kt) * 64 + lane) * 8);
            acc[nt] = __builtin_amdgcn_mfma_f32_16x16x32_bf16(areg[kt], bfrag, acc[nt], 0, 0, 0);
        }
    }

    #pragma unroll
    for (int nt = 0; nt < NT; ++nt) {
        int col = nt * 16 + r;
        float bj = bias[col];
        #pragma unroll
        for (int q = 0; q < 4; ++q) {
            long orow = m0 + quad * 4 + q;
            if (orow < N_NODES) {
                float v = fmaxf(acc[nt][q] + bj, 0.f);
                if (OUT_BF16) ((ushort_t*)outv)[orow * NOUT + col] = f2bf(v);
                else          ((float*)outv)[orow * NOUT + col] = v;
            }
        }
    }
}

// ---------------- MFMA GEMM (K=128): out = [relu]( A @ packedW [+ Cpre] [+ b] ) ----------------
template<int NOUT, bool OUT_BF16, bool PRELOAD, bool HASBIAS, bool RELU>
__global__ __launch_bounds__(256) void mfma_gemm_k128_kernel(
        const ushort_t* __restrict__ A, const ushort_t* __restrict__ pack,
        const float* __restrict__ bias, const ushort_t* __restrict__ Cpre,
        void* __restrict__ outv) {
    constexpr int NT = NOUT / 16;
    int lane = threadIdx.x & 63;
    int wave = threadIdx.x >> 6;
    long m0 = (long)blockIdx.x * 64 + wave * 16;
    int r = lane & 15;
    int quad = lane >> 4;
    long arow = m0 + r;
    if (arow > N_NODES - 1) arow = N_NODES - 1;

    bf16x8 areg[4];
    #pragma unroll
    for (int kt = 0; kt < 4; ++kt)
        areg[kt] = *(const bf16x8*)(A + arow * 128 + kt * 32 + quad * 8);

    f32x4 acc[NT];
    #pragma unroll
    for (int nt = 0; nt < NT; ++nt) {
        if (PRELOAD) {
            int col = nt * 16 + r;
            #pragma unroll
            for (int q = 0; q < 4; ++q) {
                long row = m0 + quad * 4 + q;
                if (row > N_NODES - 1) row = N_NODES - 1;
                acc[nt][q] = bf2f(Cpre[row * NOUT + col]);
            }
        } else {
            acc[nt] = (f32x4){0.f, 0.f, 0.f, 0.f};
        }
    }

    #pragma unroll
    for (int nt = 0; nt < NT; ++nt) {
        #pragma unroll
        for (int kt = 0; kt < 4; ++kt) {
            bf16x8 bfrag = *(const bf16x8*)(pack + ((long)(nt * 4 + kt) * 64 + lane) * 8);
            acc[nt] = __builtin_amdgcn_mfma_f32_16x16x32_bf16(areg[kt], bfrag, acc[nt], 0, 0, 0);
        }
    }

    #pragma unroll
    for (int nt = 0; nt < NT; ++nt) {
        int col = nt * 16 + r;
        float bj = HASBIAS ? bias[col] : 0.f;
        #pragma unroll
        for (int q = 0; q < 4; ++q) {
            long orow = m0 + quad * 4 + q;
            if (orow < N_NODES) {
                float v = acc[nt][q] + bj;
                if (RELU) v = fmaxf(v, 0.f);
                if (OUT_BF16) ((ushort_t*)outv)[orow * NOUT + col] = f2bf(v);
                else          ((float*)outv)[orow * NOUT + col] = v;
            }
        }
    }
}

extern "C" void kernel_launch(void* const* d_in, const int* in_sizes, int n_in,
                              void* d_out, int out_size, void* d_ws, size_t ws_size,
                              hipStream_t stream) {
    const float* x    = (const float*)d_in[0];
    const int*   ei   = (const int*)d_in[1];
    const float* W1_l = (const float*)d_in[2];
    const float* W1_r = (const float*)d_in[3];
    const float* b1   = (const float*)d_in[4];
    const float* W2_l = (const float*)d_in[5];
    const float* W2_r = (const float*)d_in[6];
    const float* b2   = (const float*)d_in[7];
    float* out = (float*)d_out;

    const int* src = ei;
    const int* dst = ei + N_EDGES;

    // workspace layout (16B aligned). g/meang alias mean1; x_fp8 aliases hb
    // (x_fp8 dead before mfma_mlp writes hb).
    int*  gCur   = (int*)d_ws;                        // 512
    int2* off2   = (int2*)(gCur + 512);               // 100608 int2
    int*  bedges = (int*)(off2 + 100608);             // NB*CAP
    int*  csr    = bedges + NB * CAP;                 // NB*CAP
    ushort_t* xb    = (ushort_t*)(csr + NB * CAP);    // 25.6 MB row-major [N][128]
    ushort_t* mean1 = xb + (long)N_NODES * 128;       // 25.6 MB region
    ushort_t* g     = mean1;                          // alias (12.8 MB, after mean1 dead)
    ushort_t* meang = mean1 + (long)N_NODES * 64;     // alias upper half (12.8 MB)
    ushort_t* hb    = mean1 + (long)N_NODES * 128;    // 25.6 MB row-major [N][128]
    uchar_t*  x8    = (uchar_t*)hb;                   // alias: 12.8 MB fp8 [N][128]
    ushort_t* pack1  = hb + (long)N_NODES * 128;      // 256*128 bf16
    ushort_t* pack2l = pack1 + 256 * 128;             // 128*64
    ushort_t* pack2r = pack2l + 128 * 64;             // 128*64

    // ---- CSR build (fixed-stride buckets) ----
    init_cursor_kernel<<<2, 256, 0, stream>>>(gCur);
    bucket_scatter_kernel<<<PART_BLOCKS, 256, 0, stream>>>(src, dst, gCur, bedges);
    bucket_sort_kernel<<<NB, 256, 0, stream>>>(gCur, bedges, csr, off2);

    // ---- precision prep ----
    cvt_bf16_kernel<<<((long)N_NODES * 128 / 8 + 255) / 256, 256, 0, stream>>>(
        x, xb, (long)N_NODES * 128);
    cvt_fp8_kernel<<<((long)N_NODES * 128 / 8 + 255) / 256, 256, 0, stream>>>(
        x, x8, (long)N_NODES * 128);
    pack_w_kernel<<<((128 / 16) * 8 * 64 + 255) / 256, 256, 0, stream>>>(W1_l, W1_r, pack1, 128);
    pack_wk128_kernel<<<((64 / 16) * 4 * 64 + 255) / 256, 256, 0, stream>>>(W2_l, pack2l, 64);
    pack_wk128_kernel<<<((64 / 16) * 4 * 64 + 255) / 256, 256, 0, stream>>>(W2_r, pack2r, 64);

    // ---- layer 1: mean1 = gather(x_fp8); h = relu([mean1|x]@W1 + b1) ----
    gather_mean_fp8_kernel<<<(N_NODES + 31) / 32, 256, 0, stream>>>(off2, csr, x8, mean1);
    mfma_mlp_kernel<128, true><<<(N_NODES + 63) / 64, 256, 0, stream>>>(mean1, xb, pack1, b1, hb);

    // ---- layer 2: g = h@W2_l; meang = gather(g); out = relu(meang + h@W2_r + b2) ----
    mfma_gemm_k128_kernel<64, true, false, false, false><<<(N_NODES + 63) / 64, 256, 0, stream>>>(
        hb, pack2l, nullptr, nullptr, g);
    gather_mean64_kernel<<<(N_NODES + 31) / 32, 256, 0, stream>>>(off2, csr, g, meang);
    mfma_gemm_k128_kernel<64, false, true, true, true><<<(N_NODES + 63) / 64, 256, 0, stream>>>(
        hb, pack2r, b2, meang, out);
}